// Round 2
// baseline (411.792 us; speedup 1.0000x reference)
//
#include <hip/hip_runtime.h>
#include <math.h>

typedef unsigned int uint32;
typedef unsigned long long uint64;

#define NN      16384   // row length
#define THREADS 256
#define VPT     16      // float4 loads per thread (64 elements/thread)
#define NCOPY   16      // histogram copies to reduce LDS atomic contention
#define HSTRIDE 17      // padded stride: conflict-free copy-combine reads
#define EQ_CAP  256     // capacity for ==threshold index list

// Near-correctly-rounded float log, computed in double (~25 fp64 ops vs ~100
// for library log(double)). Two paths:
//  - |x-1| < 2^-6: log1p Taylor deg-10 on exact f=x-1 (handles cancellation;
//    this is where the top-k-critical u~1 elements live).
//  - else: 128-entry table: log(x) = e*ln2 - log(rcp_c) + log1p(m*rcp_c - 1),
//    |r| <= 2^-8, deg-6 poly. Abs err ~1e-15 << half-ulp budget (>=2e-10).
__device__ __forceinline__ float cr_logf(float x, const double2* __restrict__ tab)
{
    const float d = x - 1.0f;
    if (fabsf(d) < 0.015625f) {
        const double f = (double)d;            // exact
        double q;
        q = -1.0/10.0;
        q = fma(q, f,  1.0/9.0);
        q = fma(q, f, -1.0/8.0);
        q = fma(q, f,  1.0/7.0);
        q = fma(q, f, -1.0/6.0);
        q = fma(q, f,  1.0/5.0);
        q = fma(q, f, -1.0/4.0);
        q = fma(q, f,  1.0/3.0);
        q = fma(q, f, -1.0/2.0);
        return (float)fma(f*f, q, f);
    }
    const uint32 xb = __float_as_uint(x);
    const int    e  = (int)(xb >> 23) - 127;
    const uint32 mb = xb & 0x7FFFFFu;
    const float  mf = __uint_as_float(mb | 0x3F800000u);   // m in [1,2)
    const double2 t = tab[mb >> 16];                       // {rcp_c, -log(rcp_c)}
    const double r  = fma((double)mf, t.x, -1.0);          // |r| <= 2^-8
    double q;
    q = -1.0/6.0;
    q = fma(q, r,  1.0/5.0);
    q = fma(q, r, -1.0/4.0);
    q = fma(q, r,  1.0/3.0);
    q = fma(q, r, -1.0/2.0);
    const double lm = fma(r*r, q, r) + t.y;
    return (float)fma((double)e, 0x1.62e42fefa39efp-1, lm);
}

__global__ __launch_bounds__(THREADS)
void imle_topk_kernel(const float* __restrict__ logits,
                      const float* __restrict__ noise,
                      const int*   __restrict__ kptr,
                      float*       __restrict__ out,
                      int Brows)
{
    __shared__ double2 tab[128];
    __shared__ int     hist[256 * HSTRIDE];
    __shared__ int     finalh[256];
    __shared__ uint32  sh_pref;
    __shared__ int     sh_rem;
    __shared__ int     eq_cnt;
    __shared__ int     eq_idx[EQ_CAP];

    const int row  = blockIdx.x;          // 0 .. S*B-1
    const int lrow = row % Brows;         // logits row
    const int tid  = threadIdx.x;
    const int k    = kptr[0];
    const int lane = tid & 63;
    const int wid  = tid >> 6;

    if (tid < 128) {
        const double mc  = 1.0 + ((double)(2 * tid + 1)) * (1.0 / 256.0);
        const double rcp = 1.0 / mc;
        tab[tid] = make_double2(rcp, -log(rcp));
    }
    if (tid == 0) eq_cnt = 0;
    __syncthreads();

    const float4* __restrict__ np4 = (const float4*)(noise  + (size_t)row  * NN);
    const float4* __restrict__ lp4 = (const float4*)(logits + (size_t)lrow * NN);
    float4*       __restrict__ op4 = (float4*)(out + (size_t)row * NN);

    // ---- 1. load + perturb -> sortable uint keys in registers ----
    uint32 key[VPT][4];

    #pragma unroll 4
    for (int j = 0; j < VPT; ++j) {
        const int v = tid + j * THREADS;
        const float4 u4 = np4[v];
        const float4 l4 = lp4[v];
        const float uu[4] = {u4.x, u4.y, u4.z, u4.w};
        const float ll[4] = {l4.x, l4.y, l4.z, l4.w};
        #pragma unroll
        for (int c = 0; c < 4; ++c) {
            const float t1 = cr_logf(uu[c], tab);   // log(u)       (fp32 round)
            const float t2 = cr_logf(-t1,  tab);    // log(-log(u)) (fp32 round)
            const float p  = ll[c] - t2;            // logits + gumbel
            const uint32 b = __float_as_uint(p);
            key[j][c] = (b & 0x80000000u) ? ~b : (b | 0x80000000u);
        }
    }

    // ---- 2. exact k-th largest via 4x8-bit radix select ----
    uint32 prefix = 0, himask = 0;
    int    rem    = k;
    const int copy = tid & (NCOPY - 1);

    #pragma unroll
    for (int dgt = 3; dgt >= 0; --dgt) {
        const int sh = 8 * dgt;

        #pragma unroll
        for (int i = 0; i < (256 * HSTRIDE + THREADS - 1) / THREADS; ++i) {
            const int a = tid + i * THREADS;
            if (a < 256 * HSTRIDE) hist[a] = 0;
        }
        __syncthreads();

        #pragma unroll
        for (int j = 0; j < VPT; ++j) {
            #pragma unroll
            for (int c = 0; c < 4; ++c) {
                const uint32 kk = key[j][c];
                if ((kk & himask) == prefix)
                    atomicAdd(&hist[(((kk >> sh) & 255u) * HSTRIDE) + copy], 1);
            }
        }
        __syncthreads();

        {   // combine copies: one bin per thread (stride 17 -> conflict-free)
            int ssum = 0;
            #pragma unroll
            for (int q = 0; q < NCOPY; ++q) ssum += hist[tid * HSTRIDE + q];
            finalh[tid] = ssum;
        }
        __syncthreads();

        // wave-parallel suffix scan (wave 0): find highest bin b with
        // suffix_count(b) >= rem
        if (wid == 0) {
            const int lo = 252 - 4 * lane;       // lane 0 covers top bins
            const int s  = finalh[lo] + finalh[lo+1] + finalh[lo+2] + finalh[lo+3];
            int p = s;
            #pragma unroll
            for (int off = 1; off < 64; off <<= 1) {
                const int v = __shfl_up(p, off);
                if (lane >= off) p += v;
            }
            const uint64 bal = __ballot(p >= rem);
            const int l0 = __ffsll((long long)bal) - 1;
            if (lane == l0) {
                int acc = p - s;                 // exclusive (bins above group)
                int b   = lo + 3;
                for (;;) {
                    const int h = finalh[b];
                    if (acc + h >= rem || b == lo) break;
                    acc += h; --b;
                }
                sh_pref = prefix | ((uint32)b << sh);
                sh_rem  = rem - acc;
            }
        }
        __syncthreads();
        prefix = sh_pref;
        rem    = sh_rem;
        himask |= (0xFFu << sh);
    }

    const uint32 T     = prefix;   // exact key of the k-th largest
    const int    tneed = rem;      // how many ==T to select (lowest indices)

    // ---- 3. write mask; collect ==T indices ----
    #pragma unroll
    for (int j = 0; j < VPT; ++j) {
        const int v = tid + j * THREADS;
        float o[4];
        #pragma unroll
        for (int c = 0; c < 4; ++c) {
            const uint32 kk = key[j][c];
            o[c] = (kk > T) ? 1.0f : 0.0f;
            if (kk == T) {
                const int slot = atomicAdd(&eq_cnt, 1);
                if (slot < EQ_CAP) eq_idx[slot] = 4 * v + c;
            }
        }
        op4[v] = make_float4(o[0], o[1], o[2], o[3]);
    }
    __syncthreads();

    // ---- 4. tie-break: lowest tneed indices among ==T get 1.0 ----
    if (tid == 0) {
        int e = eq_cnt; if (e > EQ_CAP) e = EQ_CAP;
        float* orow = out + (size_t)row * NN;
        for (int it = 0; it < tneed; ++it) {
            int mn = 0x7FFFFFFF, mpos = -1;
            for (int q = 0; q < e; ++q) {
                const int idx = eq_idx[q];
                if (idx >= 0 && idx < mn) { mn = idx; mpos = q; }
            }
            if (mpos < 0) break;
            eq_idx[mpos] = -1;
            orow[mn] = 1.0f;
        }
    }
}

extern "C" void kernel_launch(void* const* d_in, const int* in_sizes, int n_in,
                              void* d_out, int out_size, void* d_ws, size_t ws_size,
                              hipStream_t stream) {
    const float* logits = (const float*)d_in[0];
    const float* noise  = (const float*)d_in[1];
    const int*   kptr   = (const int*)d_in[2];
    float*       out    = (float*)d_out;

    const int rows  = in_sizes[1] / NN;   // S*B = 2048
    const int Brows = in_sizes[0] / NN;   // B   = 128

    imle_topk_kernel<<<rows, THREADS, 0, stream>>>(logits, noise, kptr, out, Brows);
}